// Round 13
// baseline (89.990 us; speedup 1.0000x reference)
//
#include <hip/hip_runtime.h>

// Cost volume: out[b,d,h,w] = (1/C) * sum_c L[b,c,h,w] * R[b,c,h,w-d], zero for w<d.
// B=8, C=128, H=96, W=320, D=48, fp32.
//
// Round 13: r8 champion (barrier-free wave-private, 67.5us) + L PREFETCH.
// r12's MFMA arc is latency-dead (~6 waves/CU dispatch cap, nothing >15% busy).
// r8's last unforced stall: L float4s issued & consumed in the SAME chunk
// (~900cyc latency vs ~700cyc cover). Fix: L prefetched one chunk ahead into a
// second named reg set (hand-unrolled x2 LA/LB ping-pong; static indices).
// Per chunk: issue L(t+1)+R(t+1) -> compute(t) from in-reg L + private LDS R
// (zero-wait start) -> pack/write R(t+1). R timing unchanged from r8.
//
// Wave layout: lane = (dq<<4)|lq; lq: 16 w-groups x 4w, dq: 4 d-groups x 12d.
// R window per 8-ch chunk: 4 f16-pair rows x 128 cols [wbase-48, wbase+80).
// Boundary: stage addrs clamped to [0,316]; invalid (w<d) zeroed at store.

typedef _Float16 h2 __attribute__((ext_vector_type(2)));

#if __has_builtin(__builtin_amdgcn_fdot2)
__device__ __forceinline__ float FDOT2(unsigned a, unsigned b, float c) {
  h2 ha, hb; __builtin_memcpy(&ha, &a, 4); __builtin_memcpy(&hb, &b, 4);
  return __builtin_amdgcn_fdot2(ha, hb, c, false);
}
#else
__device__ __forceinline__ float FDOT2(unsigned a, unsigned b, float c) {
  h2 ha, hb; __builtin_memcpy(&ha, &a, 4); __builtin_memcpy(&hb, &b, 4);
  c += (float)ha.x * (float)hb.x;
  c += (float)ha.y * (float)hb.y;
  return c;
}
#endif

__device__ __forceinline__ unsigned pack2(float x, float y) {
  h2 v; v.x = (_Float16)x; v.y = (_Float16)y;
  unsigned u; __builtin_memcpy(&u, &v, 4); return u;
}

constexpr int Cn = 128, Hn = 96, Wn = 320, Dn = 48;
constexpr int NCH = 16;               // chunks of 8 channels (4 f16-pair rows)
constexpr int PRW = 128;              // u32 cols per pair-row window
constexpr size_t planeHW = (size_t)Hn * Wn;   // 30720

__device__ __forceinline__
void compute_chunk(const unsigned* __restrict__ bufb,  // &myb[buf][0][0]
                   int j0,
                   float4 lv0, float4 lv1, float4 lv2, float4 lv3,
                   float4 lv4, float4 lv5, float4 lv6, float4 lv7,
                   float (*acc)[4]) {
#pragma unroll
  for (int pr = 0; pr < 4; ++pr) {
    const float4 lE = (pr == 0) ? lv0 : (pr == 1) ? lv2 : (pr == 2) ? lv4 : lv6;
    const float4 lO = (pr == 0) ? lv1 : (pr == 1) ? lv3 : (pr == 2) ? lv5 : lv7;
    unsigned lp[4];
    lp[0] = pack2(lE.x, lO.x); lp[1] = pack2(lE.y, lO.y);
    lp[2] = pack2(lE.z, lO.z); lp[3] = pack2(lE.w, lO.w);
    const unsigned* prow = bufb + pr * PRW;
    unsigned q[16];
#pragma unroll
    for (int tt = 0; tt < 4; ++tt) {
      const uint4 qq = *(const uint4*)(prow + j0 + 4 * tt);
      q[4 * tt + 0] = qq.x; q[4 * tt + 1] = qq.y;
      q[4 * tt + 2] = qq.z; q[4 * tt + 3] = qq.w;
    }
    // d=d0+k, w=w0+i -> R column w0+i-d0-k = pair-row index j0 + (i-k+12)
#pragma unroll
    for (int k = 0; k < 12; ++k)
#pragma unroll
      for (int i = 0; i < 4; ++i)
        acc[k][i] = FDOT2(lp[i], q[i - k + 12], acc[k][i]);
  }
}

__global__ __launch_bounds__(256)
void costvol_kernel(const float* __restrict__ L, const float* __restrict__ R,
                    float* __restrict__ out) {
  __shared__ unsigned smem[4][2][4][PRW];   // [wave][buf][pair][128] = 16 KB

  const int tid = threadIdx.x;
  const int wid = tid >> 6, lane = tid & 63;
  const int gw = blockIdx.x * 4 + wid;       // 3840 waves = 768 (b,h) x 5 w-slots
  const int bh = gw / 5, ws = gw - bh * 5;
  const int b = bh / Hn, h = bh - b * Hn;
  const int wbase = ws * 64;

  const int lq = lane & 15, dq = lane >> 4;
  const int w0 = wbase + 4 * lq;             // this lane's 4 w's
  const int d0 = 12 * dq;                    // this lane's 12 d's
  const int j0 = 4 * lq - 12 * dq + 36;      // q window base in pair-row (0..96)

  // Stage mapping: lanes 0..31 -> pair sp=0, lanes 32..63 -> sp=1, col 4*sl.
  const int sl = lane & 31, sp = lane >> 5;
  int co = wbase + 4 * sl - 48;              // 4-aligned window column
  co = co < 0 ? 0 : (co > 316 ? 316 : co);   // clamp: garbage in don't-care slots

  const size_t rowR = (size_t)b * Cn * planeHW + (size_t)h * Wn;
  const float* Re0 = R + rowR + (size_t)(2 * sp) * planeHW + co;       // pairs 0,1
  const float* Re1 = R + rowR + (size_t)(4 + 2 * sp) * planeHW + co;   // pairs 2,3
  const float* Lb  = L + rowR + w0;

  unsigned (*myb)[4][PRW] = smem[wid];       // wave-private

  float acc[12][4];
#pragma unroll
  for (int k = 0; k < 12; ++k)
#pragma unroll
    for (int i = 0; i < 4; ++i) acc[k][i] = 0.f;

  // ---- prologue: L(0) -> LA; stage R(0) into buf 0 ----
  float4 la0 = *(const float4*)(Lb + 0 * planeHW);
  float4 la1 = *(const float4*)(Lb + 1 * planeHW);
  float4 la2 = *(const float4*)(Lb + 2 * planeHW);
  float4 la3 = *(const float4*)(Lb + 3 * planeHW);
  float4 la4 = *(const float4*)(Lb + 4 * planeHW);
  float4 la5 = *(const float4*)(Lb + 5 * planeHW);
  float4 la6 = *(const float4*)(Lb + 6 * planeHW);
  float4 la7 = *(const float4*)(Lb + 7 * planeHW);
  float4 lb0, lb1, lb2, lb3, lb4, lb5, lb6, lb7;
  {
    const float4 e0 = *(const float4*)(Re0);
    const float4 o0 = *(const float4*)(Re0 + planeHW);
    const float4 e1 = *(const float4*)(Re1);
    const float4 o1 = *(const float4*)(Re1 + planeHW);
    uint4 u0, u1;
    u0.x = pack2(e0.x, o0.x); u0.y = pack2(e0.y, o0.y);
    u0.z = pack2(e0.z, o0.z); u0.w = pack2(e0.w, o0.w);
    u1.x = pack2(e1.x, o1.x); u1.y = pack2(e1.y, o1.y);
    u1.z = pack2(e1.z, o1.z); u1.w = pack2(e1.w, o1.w);
    *(uint4*)&myb[0][sp][4 * sl] = u0;
    *(uint4*)&myb[0][2 + sp][4 * sl] = u1;
  }

  for (int t = 0; t < NCH; t += 2) {
    // ================= chunk t (even): uses LA + buf[t&1=0-parity] =================
    {
      const int buf = t & 1;
      float4 e0, o0, e1, o1;
      if (t + 1 < NCH) {
        const float* Ln = Lb + (size_t)(8 * (t + 1)) * planeHW;
        lb0 = *(const float4*)(Ln + 0 * planeHW);
        lb1 = *(const float4*)(Ln + 1 * planeHW);
        lb2 = *(const float4*)(Ln + 2 * planeHW);
        lb3 = *(const float4*)(Ln + 3 * planeHW);
        lb4 = *(const float4*)(Ln + 4 * planeHW);
        lb5 = *(const float4*)(Ln + 5 * planeHW);
        lb6 = *(const float4*)(Ln + 6 * planeHW);
        lb7 = *(const float4*)(Ln + 7 * planeHW);
        const size_t coff = (size_t)(8 * (t + 1)) * planeHW;
        e0 = *(const float4*)(Re0 + coff);
        o0 = *(const float4*)(Re0 + coff + planeHW);
        e1 = *(const float4*)(Re1 + coff);
        o1 = *(const float4*)(Re1 + coff + planeHW);
      }
      compute_chunk(&myb[buf][0][0], j0, la0, la1, la2, la3, la4, la5, la6, la7, acc);
      if (t + 1 < NCH) {
        uint4 u0, u1;
        u0.x = pack2(e0.x, o0.x); u0.y = pack2(e0.y, o0.y);
        u0.z = pack2(e0.z, o0.z); u0.w = pack2(e0.w, o0.w);
        u1.x = pack2(e1.x, o1.x); u1.y = pack2(e1.y, o1.y);
        u1.z = pack2(e1.z, o1.z); u1.w = pack2(e1.w, o1.w);
        *(uint4*)&myb[buf ^ 1][sp][4 * sl] = u0;
        *(uint4*)&myb[buf ^ 1][2 + sp][4 * sl] = u1;
      }
    }
    // ================= chunk t+1 (odd): uses LB + other buf =================
    if (t + 1 < NCH) {
      const int buf = (t + 1) & 1;
      float4 e0, o0, e1, o1;
      if (t + 2 < NCH) {
        const float* Ln = Lb + (size_t)(8 * (t + 2)) * planeHW;
        la0 = *(const float4*)(Ln + 0 * planeHW);
        la1 = *(const float4*)(Ln + 1 * planeHW);
        la2 = *(const float4*)(Ln + 2 * planeHW);
        la3 = *(const float4*)(Ln + 3 * planeHW);
        la4 = *(const float4*)(Ln + 4 * planeHW);
        la5 = *(const float4*)(Ln + 5 * planeHW);
        la6 = *(const float4*)(Ln + 6 * planeHW);
        la7 = *(const float4*)(Ln + 7 * planeHW);
        const size_t coff = (size_t)(8 * (t + 2)) * planeHW;
        e0 = *(const float4*)(Re0 + coff);
        o0 = *(const float4*)(Re0 + coff + planeHW);
        e1 = *(const float4*)(Re1 + coff);
        o1 = *(const float4*)(Re1 + coff + planeHW);
      }
      compute_chunk(&myb[buf][0][0], j0, lb0, lb1, lb2, lb3, lb4, lb5, lb6, lb7, acc);
      if (t + 2 < NCH) {
        uint4 u0, u1;
        u0.x = pack2(e0.x, o0.x); u0.y = pack2(e0.y, o0.y);
        u0.z = pack2(e0.z, o0.z); u0.w = pack2(e0.w, o0.w);
        u1.x = pack2(e1.x, o1.x); u1.y = pack2(e1.y, o1.y);
        u1.z = pack2(e1.z, o1.z); u1.w = pack2(e1.w, o1.w);
        *(uint4*)&myb[buf ^ 1][sp][4 * sl] = u0;
        *(uint4*)&myb[buf ^ 1][2 + sp][4 * sl] = u1;
      }
    }
  }

  // ---- store: zero the w<d positions, scale by 1/128 ----
  const float s = 1.f / 128.f;
#pragma unroll
  for (int k = 0; k < 12; ++k) {
    float4 o;
    o.x = (w0 + 0 >= d0 + k) ? acc[k][0] * s : 0.f;
    o.y = (w0 + 1 >= d0 + k) ? acc[k][1] * s : 0.f;
    o.z = (w0 + 2 >= d0 + k) ? acc[k][2] * s : 0.f;
    o.w = (w0 + 3 >= d0 + k) ? acc[k][3] * s : 0.f;
    *(float4*)(out + ((size_t)b * Dn + d0 + k) * planeHW + (size_t)h * Wn + w0) = o;
  }
}

extern "C" void kernel_launch(void* const* d_in, const int* in_sizes, int n_in,
                              void* d_out, int out_size, void* d_ws, size_t ws_size,
                              hipStream_t stream) {
  const float* Lf = (const float*)d_in[0];
  const float* Rf = (const float*)d_in[1];
  float* outp = (float*)d_out;
  // 3840 waves = 768 (b,h) x 5 w-slots; 4 waves per 256-thread block (r8 config).
  costvol_kernel<<<dim3(960), dim3(256), 0, stream>>>(Lf, Rf, outp);
}

// Round 14
// 67.790 us; speedup vs baseline: 1.3275x; 1.3275x over previous
//
#include <hip/hip_runtime.h>

// Cost volume: out[b,d,h,w] = (1/C) * sum_c L[b,c,h,w] * R[b,c,h,w-d], zero for w<d.
// B=8, C=128, H=96, W=320, D=48, fp32.
//
// Round 14: REVERT to r8 champion (barrier-free wave-private pipeline, 67.5us)
// + bijective XCD-contiguous block swizzle (the only untested low-risk delta).
// r13 lesson: L-prefetch raised VGPR 128->152, occupancy 18.8->10.3%, dur +33%.
// This kernel's stalls are covered by TLP (other waves), not per-wave ILP —
// keep VGPR at 128. r9 lesson: 1-wave blocks scatter locality (FETCH +40%);
// keep 4-wave blocks. Swizzle: 960 blocks = 8 XCDs x 120 contiguous chunks;
// adjacent blocks share R-window overlap + neighboring (b,h) rows -> same-XCD L2.
//
// Wave layout: lane = (dq<<4)|lq; lq: 16 w-groups x 4w, dq: 4 d-groups x 12d.
// R window per 8-ch chunk: 4 f16-pair rows x 128 cols [wbase-48, wbase+80).
// Boundary: stage addrs clamped to [0,316] (4-aligned -> each float4 fully-valid
// or fully-don't-care); invalid (w<d) outputs zeroed at store.

typedef _Float16 h2 __attribute__((ext_vector_type(2)));

#if __has_builtin(__builtin_amdgcn_fdot2)
__device__ __forceinline__ float FDOT2(unsigned a, unsigned b, float c) {
  h2 ha, hb; __builtin_memcpy(&ha, &a, 4); __builtin_memcpy(&hb, &b, 4);
  return __builtin_amdgcn_fdot2(ha, hb, c, false);
}
#else
__device__ __forceinline__ float FDOT2(unsigned a, unsigned b, float c) {
  h2 ha, hb; __builtin_memcpy(&ha, &a, 4); __builtin_memcpy(&hb, &b, 4);
  c += (float)ha.x * (float)hb.x;
  c += (float)ha.y * (float)hb.y;
  return c;
}
#endif

__device__ __forceinline__ unsigned pack2(float x, float y) {
  h2 v; v.x = (_Float16)x; v.y = (_Float16)y;
  unsigned u; __builtin_memcpy(&u, &v, 4); return u;
}

constexpr int Cn = 128, Hn = 96, Wn = 320, Dn = 48;
constexpr int NCH = 16;               // chunks of 8 channels (4 f16-pair rows)
constexpr int PRW = 128;              // u32 cols per pair-row window
constexpr size_t planeHW = (size_t)Hn * Wn;   // 30720

__global__ __launch_bounds__(256)
void costvol_kernel(const float* __restrict__ L, const float* __restrict__ R,
                    float* __restrict__ out) {
  __shared__ unsigned smem[4][2][4][PRW];   // [wave][buf][pair][128] = 16 KB

  const int tid = threadIdx.x;
  const int wid = tid >> 6, lane = tid & 63;
  const int bid = blockIdx.x;
  // Bijective XCD-contiguous swizzle: XCD x gets blocks [120x, 120(x+1)).
  const int swz = (bid & 7) * 120 + (bid >> 3);
  const int gw = swz * 4 + wid;              // 3840 waves = 768 (b,h) x 5 w-slots
  const int bh = gw / 5, ws = gw - bh * 5;
  const int b = bh / Hn, h = bh - b * Hn;
  const int wbase = ws * 64;

  const int lq = lane & 15, dq = lane >> 4;
  const int w0 = wbase + 4 * lq;             // this lane's 4 w's
  const int d0 = 12 * dq;                    // this lane's 12 d's
  const int j0 = 4 * lq - 12 * dq + 36;      // q window base in pair-row (0..96)

  // Stage mapping: lanes 0..31 -> pair sp=0, lanes 32..63 -> sp=1, col 4*sl.
  const int sl = lane & 31, sp = lane >> 5;
  int co = wbase + 4 * sl - 48;              // 4-aligned window column
  co = co < 0 ? 0 : (co > 316 ? 316 : co);   // clamp: garbage lands only in don't-care slots

  const size_t rowR = (size_t)b * Cn * planeHW + (size_t)h * Wn;
  const float* Re0 = R + rowR + (size_t)(2 * sp) * planeHW + co;       // pairs 0,1
  const float* Re1 = R + rowR + (size_t)(4 + 2 * sp) * planeHW + co;   // pairs 2,3
  const float* Lb  = L + rowR + w0;

  unsigned (*myb)[4][PRW] = smem[wid];       // wave-private

  float acc[12][4];
#pragma unroll
  for (int k = 0; k < 12; ++k)
#pragma unroll
    for (int i = 0; i < 4; ++i) acc[k][i] = 0.f;

  // ---- prologue: stage chunk 0 into buf 0 ----
  {
    const float4 e0 = *(const float4*)(Re0);
    const float4 o0 = *(const float4*)(Re0 + planeHW);
    const float4 e1 = *(const float4*)(Re1);
    const float4 o1 = *(const float4*)(Re1 + planeHW);
    uint4 u0, u1;
    u0.x = pack2(e0.x, o0.x); u0.y = pack2(e0.y, o0.y);
    u0.z = pack2(e0.z, o0.z); u0.w = pack2(e0.w, o0.w);
    u1.x = pack2(e1.x, o1.x); u1.y = pack2(e1.y, o1.y);
    u1.z = pack2(e1.z, o1.z); u1.w = pack2(e1.w, o1.w);
    *(uint4*)&myb[0][sp][4 * sl] = u0;
    *(uint4*)&myb[0][2 + sp][4 * sl] = u1;
  }

#pragma unroll 2
  for (int t = 0; t < NCH; ++t) {
    const int buf = t & 1;
    const float* Lc = Lb + (size_t)(8 * t) * planeHW;

    // L loads issued FIRST (so their consumption uses a counted vmcnt that
    // does not wait on the R prefetch issued below).
    float4 lv0 = *(const float4*)(Lc + 0 * planeHW);
    float4 lv1 = *(const float4*)(Lc + 1 * planeHW);
    float4 lv2 = *(const float4*)(Lc + 2 * planeHW);
    float4 lv3 = *(const float4*)(Lc + 3 * planeHW);
    float4 lv4 = *(const float4*)(Lc + 4 * planeHW);
    float4 lv5 = *(const float4*)(Lc + 5 * planeHW);
    float4 lv6 = *(const float4*)(Lc + 6 * planeHW);
    float4 lv7 = *(const float4*)(Lc + 7 * planeHW);

    // R prefetch for chunk t+1 (issue now, ds_write after compute).
    float4 e0, o0, e1, o1;
    if (t + 1 < NCH) {
      const size_t coff = (size_t)(8 * (t + 1)) * planeHW;
      e0 = *(const float4*)(Re0 + coff);
      o0 = *(const float4*)(Re0 + coff + planeHW);
      e1 = *(const float4*)(Re1 + coff);
      o1 = *(const float4*)(Re1 + coff + planeHW);
    }

    // ---- compute chunk t from wave-private buf ----
#pragma unroll
    for (int pr = 0; pr < 4; ++pr) {
      const float4 lE = (pr == 0) ? lv0 : (pr == 1) ? lv2 : (pr == 2) ? lv4 : lv6;
      const float4 lO = (pr == 0) ? lv1 : (pr == 1) ? lv3 : (pr == 2) ? lv5 : lv7;
      unsigned lp[4];
      lp[0] = pack2(lE.x, lO.x); lp[1] = pack2(lE.y, lO.y);
      lp[2] = pack2(lE.z, lO.z); lp[3] = pack2(lE.w, lO.w);
      const unsigned* prow = &myb[buf][pr][0];
      unsigned q[16];
#pragma unroll
      for (int tt = 0; tt < 4; ++tt) {
        const uint4 qq = *(const uint4*)(prow + j0 + 4 * tt);
        q[4 * tt + 0] = qq.x; q[4 * tt + 1] = qq.y;
        q[4 * tt + 2] = qq.z; q[4 * tt + 3] = qq.w;
      }
      // d=d0+k, w=w0+i -> R column w0+i-d0-k = pair-row index j0 + (i-k+12)
#pragma unroll
      for (int k = 0; k < 12; ++k)
#pragma unroll
        for (int i = 0; i < 4; ++i)
          acc[k][i] = FDOT2(lp[i], q[i - k + 12], acc[k][i]);
    }

    // ---- write prefetched chunk t+1 into the other private buffer ----
    if (t + 1 < NCH) {
      uint4 u0, u1;
      u0.x = pack2(e0.x, o0.x); u0.y = pack2(e0.y, o0.y);
      u0.z = pack2(e0.z, o0.z); u0.w = pack2(e0.w, o0.w);
      u1.x = pack2(e1.x, o1.x); u1.y = pack2(e1.y, o1.y);
      u1.z = pack2(e1.z, o1.z); u1.w = pack2(e1.w, o1.w);
      *(uint4*)&myb[buf ^ 1][sp][4 * sl] = u0;
      *(uint4*)&myb[buf ^ 1][2 + sp][4 * sl] = u1;
    }
  }

  // ---- store: zero the w<d positions, scale by 1/128 ----
  const float s = 1.f / 128.f;
#pragma unroll
  for (int k = 0; k < 12; ++k) {
    float4 o;
    o.x = (w0 + 0 >= d0 + k) ? acc[k][0] * s : 0.f;
    o.y = (w0 + 1 >= d0 + k) ? acc[k][1] * s : 0.f;
    o.z = (w0 + 2 >= d0 + k) ? acc[k][2] * s : 0.f;
    o.w = (w0 + 3 >= d0 + k) ? acc[k][3] * s : 0.f;
    *(float4*)(out + ((size_t)b * Dn + d0 + k) * planeHW + (size_t)h * Wn + w0) = o;
  }
}

extern "C" void kernel_launch(void* const* d_in, const int* in_sizes, int n_in,
                              void* d_out, int out_size, void* d_ws, size_t ws_size,
                              hipStream_t stream) {
  const float* Lf = (const float*)d_in[0];
  const float* Rf = (const float*)d_in[1];
  float* outp = (float*)d_out;
  // 960 blocks x 4 waves = 3840 waves = 768 (b,h) x 5 w-slots.
  costvol_kernel<<<dim3(960), dim3(256), 0, stream>>>(Lf, Rf, outp);
}